// Round 4
// baseline (1161.993 us; speedup 1.0000x reference)
//
#include <hip/hip_runtime.h>

#define NN 50000
#define EE 1600000
#define INDIM 1280
#define HID 256
#define HEADS 4
#define DHD 64
#define NCLS 6
#define NEG 0.2f
#define LNEPS 1e-5f

typedef __attribute__((ext_vector_type(8))) short short8;
typedef __attribute__((ext_vector_type(4))) float floatx4;

__device__ __forceinline__ unsigned short f2b(float f) {
    unsigned int u = __float_as_uint(f);
    u += 0x7FFF + ((u >> 16) & 1);
    return (unsigned short)(u >> 16);
}
__device__ __forceinline__ float b2f(unsigned short b) {
    return __uint_as_float(((unsigned int)b) << 16);
}

// ---------------- CSR build ----------------
__global__ void init_cnt_kernel(int* __restrict__ cnt) {
    int n = blockIdx.x * 256 + threadIdx.x;
    if (n < NN) cnt[n] = 1;  // self loop
}

__global__ void count_edges_kernel(const int* __restrict__ dst, int* __restrict__ cnt) {
    int e = blockIdx.x * 256 + threadIdx.x;
    if (e < EE) atomicAdd(&cnt[dst[e]], 1);
}

__global__ __launch_bounds__(1024) void scan1_kernel(const int* __restrict__ cnt,
                                                     int* __restrict__ scanned,
                                                     int* __restrict__ chtot, int n) {
    __shared__ int wsum[16];
    int tid = threadIdx.x, lane = tid & 63, wv = tid >> 6;
    int i = blockIdx.x * 1024 + tid;
    int s = (i < n) ? cnt[i] : 0;
#pragma unroll
    for (int off = 1; off < 64; off <<= 1) {
        int t = __shfl_up(s, off, 64);
        if (lane >= off) s += t;
    }
    if (lane == 63) wsum[wv] = s;
    __syncthreads();
    if (tid < 16) {
        int ws = wsum[tid];
#pragma unroll
        for (int off = 1; off < 16; off <<= 1) {
            int t = __shfl_up(ws, off, 16);
            if (tid >= off) ws += t;
        }
        wsum[tid] = ws;
    }
    __syncthreads();
    s += (wv > 0) ? wsum[wv - 1] : 0;
    if (i < n) scanned[i] = s;
    if (tid == 1023) chtot[blockIdx.x] = s;
}

__global__ void scan2_kernel(int* __restrict__ chtot, int nch) {
    int lane = threadIdx.x;
    int v = (lane < nch) ? chtot[lane] : 0;
#pragma unroll
    for (int off = 1; off < 64; off <<= 1) {
        int t = __shfl_up(v, off, 64);
        if (lane >= off) v += t;
    }
    if (lane < nch) chtot[lane] = v;
}

__global__ void scan3_kernel(const int* __restrict__ scanned, const int* __restrict__ chtot,
                             int* __restrict__ rowptr, int n) {
    int i = blockIdx.x * 256 + threadIdx.x;
    if (i == 0) rowptr[0] = 0;
    if (i < n) {
        int ch = i >> 10;
        rowptr[i + 1] = scanned[i] + (ch ? chtot[ch - 1] : 0);
    }
}

__global__ void copyfill_kernel(const int* __restrict__ rowptr, int* __restrict__ cursor,
                                int* __restrict__ csr) {
    int n = blockIdx.x * 256 + threadIdx.x;
    if (n < NN) {
        int p = rowptr[n];
        csr[p] = n;
        cursor[n] = p + 1;
    }
}

__global__ void scatter_edges_kernel(const int* __restrict__ src, const int* __restrict__ dst,
                                     int* __restrict__ cursor, int* __restrict__ csr) {
    int e = blockIdx.x * 256 + threadIdx.x;
    if (e < EE) {
        int d = dst[e];
        int pos = atomicAdd(&cursor[d], 1);
        csr[pos] = src[e];
    }
}

// ---------------- weight pack: W[K][N] fp32 -> MFMA B-fragment order bf16 ----------------
// out[(((kc*NT + nt)*2 + ks)*64 + ln)*8 + j] = bf16(W[kc*64+ks*32+(ln>>4)*8+j][nt*16+(ln&15)])
__global__ void pack_w_kernel(const float* __restrict__ W, unsigned short* __restrict__ out,
                              int K, int N) {
    int idx = blockIdx.x * 256 + threadIdx.x;
    int total = (K >> 6) * (N >> 4) * 2 * 64;
    if (idx >= total) return;
    int ln = idx & 63;
    int t = idx >> 6;
    int ks = t & 1; t >>= 1;
    int NT = N >> 4;
    int nt = t % NT, kc = t / NT;
    int n = nt * 16 + (ln & 15);
    int k = kc * 64 + ks * 32 + ((ln >> 4) << 3);
    unsigned short u[8];
#pragma unroll
    for (int j = 0; j < 8; j++) u[j] = f2b(W[(size_t)(k + j) * N + n]);
    *(int4*)&out[(size_t)idx * 8] = *(const int4*)u;
}

// ---------------- barrier-free fragment GEMM ----------------
// C[M, NT*16] = act(A[M,K] @ W + bias). BM=64, 256 threads (4 waves), no LDS, no barriers.
// A loaded per-lane in MFMA A-frag pattern; B from pre-packed fragment buffer (coalesced).
template <int AF32, int NT, int ACT, int WF32, int WB16>
__global__ __launch_bounds__(256) void fgemm_kernel(const float* __restrict__ Af,
                                                    const unsigned short* __restrict__ Ab,
                                                    const unsigned short* __restrict__ Bf,
                                                    const float* __restrict__ bias,
                                                    float* __restrict__ Cf,
                                                    unsigned short* __restrict__ Cb,
                                                    int M, int K) {
    constexpr int NW = NT / 4;  // n-tiles per wave
    int wv = threadIdx.x >> 6, ln = threadIdx.x & 63;
    int m0 = blockIdx.x * 64;
    int kcol = (ln >> 4) << 3;

    size_t arow[4];
#pragma unroll
    for (int mt = 0; mt < 4; mt++) {
        int r = m0 + mt * 16 + (ln & 15);
        arow[mt] = (size_t)min(r, M - 1) * K;  // clamp; stores guarded below
    }

    floatx4 acc[4][NW] = {};

    for (int k0 = 0; k0 < K; k0 += 64) {
#pragma unroll
        for (int ks = 0; ks < 2; ks++) {
            int kb = k0 + ks * 32 + kcol;
            short8 a[4];
#pragma unroll
            for (int mt = 0; mt < 4; mt++) {
                if (AF32) {
                    const float* s = Af + arow[mt] + kb;
                    float4 f0 = *(const float4*)s;
                    float4 f1 = *(const float4*)(s + 4);
                    unsigned short u[8] = {f2b(f0.x), f2b(f0.y), f2b(f0.z), f2b(f0.w),
                                           f2b(f1.x), f2b(f1.y), f2b(f1.z), f2b(f1.w)};
                    a[mt] = *(const short8*)u;
                } else {
                    a[mt] = *(const short8*)(Ab + arow[mt] + kb);
                }
            }
            short8 b[NW];
#pragma unroll
            for (int nw = 0; nw < NW; nw++) {
                size_t boff = ((((size_t)(k0 >> 6) * NT + (wv * NW + nw)) * 2 + ks) * 64 + ln) * 8;
                b[nw] = *(const short8*)(Bf + boff);
            }
#pragma unroll
            for (int nw = 0; nw < NW; nw++)
#pragma unroll
                for (int mt = 0; mt < 4; mt++)
                    acc[mt][nw] = __builtin_amdgcn_mfma_f32_16x16x32_bf16(a[mt], b[nw], acc[mt][nw], 0, 0, 0);
        }
    }

    const int Nout = NT * 16;
#pragma unroll
    for (int mt = 0; mt < 4; mt++) {
#pragma unroll
        for (int nw = 0; nw < NW; nw++) {
            int col = (wv * NW + nw) * 16 + (ln & 15);
            int rb = m0 + mt * 16 + (ln >> 4) * 4;
            float bi = bias ? bias[col] : 0.f;
#pragma unroll
            for (int r = 0; r < 4; r++) {
                int row = rb + r;
                if (row < M) {
                    float v = acc[mt][nw][r] + bi;
                    if (ACT) v = fmaxf(v, 0.f);
                    if (WF32) Cf[(size_t)row * Nout + col] = v;
                    if (WB16) Cb[(size_t)row * Nout + col] = f2b(v);
                }
            }
        }
    }
}

// ---------------- attention logits from bf16 xh ----------------
__global__ __launch_bounds__(256) void proj_al_kernel(const unsigned short* __restrict__ xhb,
                                                      const float* __restrict__ a_src,
                                                      const float* __restrict__ a_dst,
                                                      float* __restrict__ al_s,
                                                      float* __restrict__ al_d) {
    int n = blockIdx.x * 4 + (threadIdx.x >> 6);
    if (n >= NN) return;
    int lane = threadIdx.x & 63;
    ushort4 v4 = ((const ushort4*)(xhb + (size_t)n * HID))[lane];
    int base = lane * 4;
    float4 as4 = *(const float4*)&a_src[base];
    float4 ad4 = *(const float4*)&a_dst[base];
    float x0 = b2f(v4.x), x1 = b2f(v4.y), x2 = b2f(v4.z), x3 = b2f(v4.w);
    float ps = x0 * as4.x + x1 * as4.y + x2 * as4.z + x3 * as4.w;
    float pd = x0 * ad4.x + x1 * ad4.y + x2 * ad4.z + x3 * ad4.w;
#pragma unroll
    for (int off = 8; off > 0; off >>= 1) {
        ps += __shfl_down(ps, off, 16);
        pd += __shfl_down(pd, off, 16);
    }
    if ((lane & 15) == 0) {
        int h = lane >> 4;
        al_s[n * 4 + h] = ps;
        al_d[n * 4 + h] = pd;
    }
}

// ---------------- wave-per-node: edge softmax + aggregation + LN + ReLU + residual ----------------
__global__ __launch_bounds__(256) void agg_ln_kernel(const int* __restrict__ rowptr,
                                                     const int* __restrict__ csr,
                                                     const float* __restrict__ al_s,
                                                     const float* __restrict__ al_d,
                                                     const unsigned short* __restrict__ xhb,
                                                     const float* __restrict__ bgat,
                                                     const float* __restrict__ g,
                                                     const float* __restrict__ bb,
                                                     float* __restrict__ h,
                                                     unsigned short* __restrict__ hb) {
    int wv = threadIdx.x >> 6, ln = threadIdx.x & 63;
    int n = blockIdx.x * 4 + wv;
    if (n >= NN) return;
    int start = rowptr[n], end = rowptr[n + 1];
    float4 ad = *(const float4*)&al_d[n * 4];

    float d0 = 0.f, d1 = 0.f, d2 = 0.f, d3 = 0.f;
    for (int i = start + ln; i < end; i += 64) {
        int s = csr[i];
        float4 as = *(const float4*)&al_s[s * 4];
        float e0 = as.x + ad.x; e0 = e0 > 0.f ? e0 : NEG * e0;
        float e1 = as.y + ad.y; e1 = e1 > 0.f ? e1 : NEG * e1;
        float e2 = as.z + ad.z; e2 = e2 > 0.f ? e2 : NEG * e2;
        float e3 = as.w + ad.w; e3 = e3 > 0.f ? e3 : NEG * e3;
        d0 += __expf(e0); d1 += __expf(e1); d2 += __expf(e2); d3 += __expf(e3);
    }
#pragma unroll
    for (int off = 32; off > 0; off >>= 1) {
        d0 += __shfl_xor(d0, off, 64);
        d1 += __shfl_xor(d1, off, 64);
        d2 += __shfl_xor(d2, off, 64);
        d3 += __shfl_xor(d3, off, 64);
    }
    int myh = ln >> 4;
    float invh = 1.f / ((myh == 0) ? d0 : (myh == 1) ? d1 : (myh == 2) ? d2 : d3);
    float adh = (myh == 0) ? ad.x : (myh == 1) ? ad.y : (myh == 2) ? ad.z : ad.w;

    float a0 = 0.f, a1 = 0.f, a2 = 0.f, a3 = 0.f;
#pragma unroll 2
    for (int i = start; i < end; i++) {
        int s = csr[i];
        float e = al_s[s * 4 + myh] + adh;
        e = e > 0.f ? e : NEG * e;
        float w = __expf(e) * invh;
        ushort4 mv = *(const ushort4*)&xhb[(size_t)s * HID + ln * 4];
        a0 = fmaf(w, b2f(mv.x), a0);
        a1 = fmaf(w, b2f(mv.y), a1);
        a2 = fmaf(w, b2f(mv.z), a2);
        a3 = fmaf(w, b2f(mv.w), a3);
    }

    float4 bg = *(const float4*)&bgat[ln * 4];
    float v0 = a0 + bg.x, v1 = a1 + bg.y, v2 = a2 + bg.z, v3 = a3 + bg.w;
    float ps = v0 + v1 + v2 + v3;
    float ps2 = v0 * v0 + v1 * v1 + v2 * v2 + v3 * v3;
#pragma unroll
    for (int off = 32; off > 0; off >>= 1) {
        ps += __shfl_xor(ps, off, 64);
        ps2 += __shfl_xor(ps2, off, 64);
    }
    float mu = ps * (1.f / HID);
    float var = ps2 * (1.f / HID) - mu * mu;
    float rs = rsqrtf(var + LNEPS);
    float4 gg = *(const float4*)&g[ln * 4];
    float4 bbv = *(const float4*)&bb[ln * 4];
    float o0 = fmaxf((v0 - mu) * rs * gg.x + bbv.x, 0.f);
    float o1 = fmaxf((v1 - mu) * rs * gg.y + bbv.y, 0.f);
    float o2 = fmaxf((v2 - mu) * rs * gg.z + bbv.z, 0.f);
    float o3 = fmaxf((v3 - mu) * rs * gg.w + bbv.w, 0.f);
    size_t idx = (size_t)n * HID + ln * 4;
    float4 hv = *(const float4*)&h[idx];
    float4 nh = make_float4(hv.x + o0, hv.y + o1, hv.z + o2, hv.w + o3);
    *(float4*)&h[idx] = nh;
    ushort4 nb = {f2b(nh.x), f2b(nh.y), f2b(nh.z), f2b(nh.w)};
    *(ushort4*)&hb[idx] = nb;
}

// ---------------- final tiny GEMM ----------------
__global__ void cls2_kernel(const float* __restrict__ mid, const float* __restrict__ W,
                            const float* __restrict__ bias, float* __restrict__ out) {
    int idx = blockIdx.x * 256 + threadIdx.x;
    if (idx >= NN * NCLS) return;
    int n = idx / NCLS, c = idx % NCLS;
    const float* row = mid + (size_t)n * (HID / 2);
    float acc = bias[c];
#pragma unroll 8
    for (int k = 0; k < HID / 2; k++) acc += row[k] * W[k * NCLS + c];
    out[idx] = acc;
}

extern "C" void kernel_launch(void* const* d_in, const int* in_sizes, int n_in,
                              void* d_out, int out_size, void* d_ws, size_t ws_size,
                              hipStream_t stream) {
    const float* x    = (const float*)d_in[0];
    const int*   ei   = (const int*)d_in[1];
    const float* W_in = (const float*)d_in[2];
    const float* b_in = (const float*)d_in[3];
    const float* W_gat[2]   = {(const float*)d_in[4],  (const float*)d_in[10]};
    const float* att_src[2] = {(const float*)d_in[5],  (const float*)d_in[11]};
    const float* att_dst[2] = {(const float*)d_in[6],  (const float*)d_in[12]};
    const float* b_gat[2]   = {(const float*)d_in[7],  (const float*)d_in[13]};
    const float* ln_g[2]    = {(const float*)d_in[8],  (const float*)d_in[14]};
    const float* ln_b[2]    = {(const float*)d_in[9],  (const float*)d_in[15]};
    const float* W_c1 = (const float*)d_in[16];
    const float* b_c1 = (const float*)d_in[17];
    const float* W_c2 = (const float*)d_in[18];
    const float* b_c2 = (const float*)d_in[19];

    char* ws = (char*)d_ws;
    size_t off = 0;
    auto alloc = [&](size_t bytes) -> void* {
        void* p = ws + off;
        off += (bytes + 255) & ~(size_t)255;
        return p;
    };
    float*          h   = (float*)alloc((size_t)NN * HID * 4);
    unsigned short* hb  = (unsigned short*)alloc((size_t)NN * HID * 2);
    unsigned short* xhb = (unsigned short*)alloc((size_t)NN * HID * 2);
    float* al_s = (float*)alloc((size_t)NN * HEADS * 4);
    float* al_d = (float*)alloc((size_t)NN * HEADS * 4);
    int* rowptr  = (int*)alloc((size_t)(NN + 1) * 4);
    int* cursor  = (int*)alloc((size_t)NN * 4);
    int* csr     = (int*)alloc((size_t)(EE + NN) * 4);
    int* scanned = (int*)alloc((size_t)NN * 4);
    int* chtot   = (int*)alloc(64 * 4);
    unsigned short* WinF = (unsigned short*)alloc((size_t)HID * INDIM * 2);
    unsigned short* WgF0 = (unsigned short*)alloc((size_t)HID * HID * 2);
    unsigned short* WgF1 = (unsigned short*)alloc((size_t)HID * HID * 2);
    unsigned short* Wc1F = (unsigned short*)alloc((size_t)(HID / 2) * HID * 2);
    unsigned short* WgF[2] = {WgF0, WgF1};
    float* mid = (float*)xhb;

    const int* srcv = ei;
    const int* dstv = ei + EE;

    // weight packs (fp32 [K][N] -> bf16 MFMA B-fragment order)
    pack_w_kernel<<<(INDIM * HID / 8 + 255) / 256, 256, 0, stream>>>(W_in, WinF, INDIM, HID);
    pack_w_kernel<<<(HID * HID / 8 + 255) / 256, 256, 0, stream>>>(W_gat[0], WgF0, HID, HID);
    pack_w_kernel<<<(HID * HID / 8 + 255) / 256, 256, 0, stream>>>(W_gat[1], WgF1, HID, HID);
    pack_w_kernel<<<(HID * (HID / 2) / 8 + 255) / 256, 256, 0, stream>>>(W_c1, Wc1F, HID, HID / 2);

    // CSR build
    int nch = (NN + 1023) / 1024;
    init_cnt_kernel<<<(NN + 255) / 256, 256, 0, stream>>>(cursor);
    count_edges_kernel<<<(EE + 255) / 256, 256, 0, stream>>>(dstv, cursor);
    scan1_kernel<<<nch, 1024, 0, stream>>>(cursor, scanned, chtot, NN);
    scan2_kernel<<<1, 64, 0, stream>>>(chtot, nch);
    scan3_kernel<<<(NN + 255) / 256, 256, 0, stream>>>(scanned, chtot, rowptr, NN);
    copyfill_kernel<<<(NN + 255) / 256, 256, 0, stream>>>(rowptr, cursor, csr);
    scatter_edges_kernel<<<(EE + 255) / 256, 256, 0, stream>>>(srcv, dstv, cursor, csr);

    int MB64 = (NN + 63) / 64;  // 782

    // h = relu(x @ W_in + b_in): fp32 A direct, barrier-free
    fgemm_kernel<1, 16, 1, 1, 1><<<MB64, 256, 0, stream>>>(
        x, nullptr, WinF, b_in, h, hb, NN, INDIM);

    for (int l = 0; l < 2; l++) {
        fgemm_kernel<0, 16, 0, 0, 1><<<MB64, 256, 0, stream>>>(
            nullptr, hb, WgF[l], nullptr, nullptr, xhb, NN, HID);
        proj_al_kernel<<<(NN + 3) / 4, 256, 0, stream>>>(xhb, att_src[l], att_dst[l], al_s, al_d);
        agg_ln_kernel<<<(NN + 3) / 4, 256, 0, stream>>>(rowptr, csr, al_s, al_d, xhb,
                                                        b_gat[l], ln_g[l], ln_b[l], h, hb);
    }

    // classifier
    fgemm_kernel<0, 8, 1, 1, 0><<<MB64, 256, 0, stream>>>(
        nullptr, hb, Wc1F, b_c1, mid, nullptr, NN, HID);
    cls2_kernel<<<(NN * NCLS + 255) / 256, 256, 0, stream>>>(mid, W_c2, b_c2, (float*)d_out);
}

// Round 5
// 1039.000 us; speedup vs baseline: 1.1184x; 1.1184x over previous
//
#include <hip/hip_runtime.h>

#define NN 50000
#define EE 1600000
#define INDIM 1280
#define HID 256
#define HEADS 4
#define DHD 64
#define NCLS 6
#define NEG 0.2f
#define LNEPS 1e-5f

typedef __attribute__((ext_vector_type(8))) short short8;
typedef __attribute__((ext_vector_type(4))) float floatx4;

__device__ __forceinline__ unsigned short f2b(float f) {
    unsigned int u = __float_as_uint(f);
    u += 0x7FFF + ((u >> 16) & 1);
    return (unsigned short)(u >> 16);
}
__device__ __forceinline__ float b2f(unsigned short b) {
    return __uint_as_float(((unsigned int)b) << 16);
}

// s_waitcnt lgkmcnt(0), vmcnt/expcnt no-wait: vm=63 -> [3:0]=0xF,[15:14]=3; exp=7 -> [6:4]; lgkm=0 -> [11:8]
#define WAIT_LGKM0() __builtin_amdgcn_s_waitcnt(0xC07F)

// ---------------- CSR build ----------------
__global__ void init_cnt_kernel(int* __restrict__ cnt) {
    int n = blockIdx.x * 256 + threadIdx.x;
    if (n < NN) cnt[n] = 1;  // self loop
}

__global__ void count_edges_kernel(const int* __restrict__ dst, int* __restrict__ cnt) {
    int e = blockIdx.x * 256 + threadIdx.x;
    if (e < EE) atomicAdd(&cnt[dst[e]], 1);
}

__global__ __launch_bounds__(1024) void scan1_kernel(const int* __restrict__ cnt,
                                                     int* __restrict__ scanned,
                                                     int* __restrict__ chtot, int n) {
    __shared__ int wsum[16];
    int tid = threadIdx.x, lane = tid & 63, wv = tid >> 6;
    int i = blockIdx.x * 1024 + tid;
    int s = (i < n) ? cnt[i] : 0;
#pragma unroll
    for (int off = 1; off < 64; off <<= 1) {
        int t = __shfl_up(s, off, 64);
        if (lane >= off) s += t;
    }
    if (lane == 63) wsum[wv] = s;
    __syncthreads();
    if (tid < 16) {
        int ws = wsum[tid];
#pragma unroll
        for (int off = 1; off < 16; off <<= 1) {
            int t = __shfl_up(ws, off, 16);
            if (tid >= off) ws += t;
        }
        wsum[tid] = ws;
    }
    __syncthreads();
    s += (wv > 0) ? wsum[wv - 1] : 0;
    if (i < n) scanned[i] = s;
    if (tid == 1023) chtot[blockIdx.x] = s;
}

__global__ void scan2_kernel(int* __restrict__ chtot, int nch) {
    int lane = threadIdx.x;
    int v = (lane < nch) ? chtot[lane] : 0;
#pragma unroll
    for (int off = 1; off < 64; off <<= 1) {
        int t = __shfl_up(v, off, 64);
        if (lane >= off) v += t;
    }
    if (lane < nch) chtot[lane] = v;
}

__global__ void scan3_kernel(const int* __restrict__ scanned, const int* __restrict__ chtot,
                             int* __restrict__ rowptr, int n) {
    int i = blockIdx.x * 256 + threadIdx.x;
    if (i == 0) rowptr[0] = 0;
    if (i < n) {
        int ch = i >> 10;
        rowptr[i + 1] = scanned[i] + (ch ? chtot[ch - 1] : 0);
    }
}

__global__ void copyfill_kernel(const int* __restrict__ rowptr, int* __restrict__ cursor,
                                int* __restrict__ csr) {
    int n = blockIdx.x * 256 + threadIdx.x;
    if (n < NN) {
        int p = rowptr[n];
        csr[p] = n;
        cursor[n] = p + 1;
    }
}

__global__ void scatter_edges_kernel(const int* __restrict__ src, const int* __restrict__ dst,
                                     int* __restrict__ cursor, int* __restrict__ csr) {
    int e = blockIdx.x * 256 + threadIdx.x;
    if (e < EE) {
        int d = dst[e];
        int pos = atomicAdd(&cursor[d], 1);
        csr[pos] = src[e];
    }
}

// ---------------- weight pack: W[K][N] fp32 -> MFMA B-fragment order bf16 ----------------
// out[(((kc*NT + nt)*2 + ks)*64 + ln)*8 + j] = bf16(W[kc*64+ks*32+(ln>>4)*8+j][nt*16+(ln&15)])
__global__ void pack_w_kernel(const float* __restrict__ W, unsigned short* __restrict__ out,
                              int K, int N) {
    int idx = blockIdx.x * 256 + threadIdx.x;
    int total = (K >> 6) * (N >> 4) * 2 * 64;
    if (idx >= total) return;
    int ln = idx & 63;
    int t = idx >> 6;
    int ks = t & 1; t >>= 1;
    int NT = N >> 4;
    int nt = t % NT, kc = t / NT;
    int n = nt * 16 + (ln & 15);
    int k = kc * 64 + ks * 32 + ((ln >> 4) << 3);
    unsigned short u[8];
#pragma unroll
    for (int j = 0; j < 8; j++) u[j] = f2b(W[(size_t)(k + j) * N + n]);
    *(int4*)&out[(size_t)idx * 8] = *(const int4*)u;
}

// ---------------- pipelined LDS-dbuf MFMA GEMM ----------------
// C[M, NT*16] = act(A[M,K] @ W + bias). BM=64, BK=64, 256 threads (4 waves).
// One raw s_barrier per K-iter; staging loads fire at stage-top (compiler-tracked vmcnt),
// land during compute; ds_write + lgkmcnt(0) after compute. A-LDS XOR-swizzled (bank-conflict-free).
template <int AF32, int KI, int NT, int ACT, int WF32, int WB16>
__global__ __launch_bounds__(256) void pgemm_kernel(const float* __restrict__ Af,
                                                    const unsigned short* __restrict__ Ab,
                                                    const unsigned short* __restrict__ Bf,
                                                    const float* __restrict__ bias,
                                                    float* __restrict__ Cf,
                                                    unsigned short* __restrict__ Cb,
                                                    int M) {
    constexpr int NW = NT / 4;
    constexpr int K = KI * 64;
    __shared__ __align__(16) unsigned short Als[2][4096];  // 2 x 8KB bf16 64x64 tiles
    int tid = threadIdx.x, wv = tid >> 6, ln = tid & 63;
    int m0 = blockIdx.x * 64;

    // staging geometry: thread covers 16B slots tid and tid+256 (of 512).
    // slot s -> LDS bytes [16s,16s+16); row = s>>3, stored col-group g' = s&7,
    // global col-group g = g' ^ (row&7)  (XOR swizzle).
    int srow[2], scol[2];
#pragma unroll
    for (int i = 0; i < 2; i++) {
        int s = tid + i * 256;
        int r = s >> 3;
        srow[i] = min(m0 + r, M - 1);
        scol[i] = ((s & 7) ^ (r & 7)) * 8;
    }

    floatx4 acc[4][NW] = {};
    short8 breg[2][NW * 2];
    float4 af0[4], af1[4];
    int4 ai0[2], ai1[2];

    auto issueA = [&](int k, float4* af, int4* ai) {
#pragma unroll
        for (int i = 0; i < 2; i++) {
            if (AF32) {
                const float* p = Af + (size_t)srow[i] * K + k * 64 + scol[i];
                af[i * 2] = *(const float4*)p;
                af[i * 2 + 1] = *(const float4*)(p + 4);
            } else {
                ai[i] = *(const int4*)(Ab + (size_t)srow[i] * K + k * 64 + scol[i]);
            }
        }
    };
    auto issueB = [&](int k, short8* b) {
#pragma unroll
        for (int nw = 0; nw < NW; nw++)
#pragma unroll
            for (int ks = 0; ks < 2; ks++)
                b[nw * 2 + ks] = *(const short8*)(
                    Bf + ((((size_t)k * NT + (wv * NW + nw)) * 2 + ks) * 64 + ln) * 8);
    };
    auto writeA = [&](int k, const float4* af, const int4* ai) {
        unsigned short* dst = &Als[k & 1][0];
#pragma unroll
        for (int i = 0; i < 2; i++) {
            int4 v;
            if (AF32) {
                unsigned short u[8] = {f2b(af[2 * i].x), f2b(af[2 * i].y),
                                       f2b(af[2 * i].z), f2b(af[2 * i].w),
                                       f2b(af[2 * i + 1].x), f2b(af[2 * i + 1].y),
                                       f2b(af[2 * i + 1].z), f2b(af[2 * i + 1].w)};
                v = *(const int4*)u;
            } else {
                v = ai[i];
            }
            *(int4*)&dst[(tid + i * 256) * 8] = v;
        }
    };
    auto compute = [&](int k, const short8* b) {
        const unsigned short* src = &Als[k & 1][0];
#pragma unroll
        for (int ks = 0; ks < 2; ks++) {
            short8 a[4];
#pragma unroll
            for (int mt = 0; mt < 4; mt++) {
                int row = mt * 16 + (ln & 15);
                int g = ks * 4 + (ln >> 4);
                int off8 = (row >> 3) * 512 + (row & 7) * 64 + (g ^ (row & 7)) * 8;
                a[mt] = *(const short8*)&src[off8];
            }
#pragma unroll
            for (int nw = 0; nw < NW; nw++)
#pragma unroll
                for (int mt = 0; mt < 4; mt++)
                    acc[mt][nw] = __builtin_amdgcn_mfma_f32_16x16x32_bf16(
                        a[mt], b[nw * 2 + ks], acc[mt][nw], 0, 0, 0);
        }
    };

    // prologue: stage iter 0
    issueA(0, af0, ai0);
    issueB(0, breg[0]);
    writeA(0, af0, ai0);
    WAIT_LGKM0();
    __builtin_amdgcn_s_barrier();

#pragma unroll
    for (int kk = 0; kk < KI / 2; kk++) {
        int k = kk * 2;
        // even stage: compute k, stage k+1
        issueA(k + 1, af1, ai1);
        issueB(k + 1, breg[1]);
        compute(k, breg[0]);
        writeA(k + 1, af1, ai1);
        WAIT_LGKM0();
        __builtin_amdgcn_s_barrier();
        // odd stage: compute k+1, stage k+2
        if (k + 2 < KI) {
            issueA(k + 2, af0, ai0);
            issueB(k + 2, breg[0]);
        }
        compute(k + 1, breg[1]);
        if (k + 2 < KI) {
            writeA(k + 2, af0, ai0);
            WAIT_LGKM0();
            __builtin_amdgcn_s_barrier();
        }
    }

    // epilogue: C/D layout col=lane&15, row=(lane>>4)*4+reg
    constexpr int Nout = NT * 16;
#pragma unroll
    for (int mt = 0; mt < 4; mt++) {
#pragma unroll
        for (int nw = 0; nw < NW; nw++) {
            int col = (wv * NW + nw) * 16 + (ln & 15);
            int rb = m0 + mt * 16 + (ln >> 4) * 4;
            float bi = bias ? bias[col] : 0.f;
#pragma unroll
            for (int r = 0; r < 4; r++) {
                int row = rb + r;
                if (row < M) {
                    float v = acc[mt][nw][r] + bi;
                    if (ACT) v = fmaxf(v, 0.f);
                    if (WF32) Cf[(size_t)row * Nout + col] = v;
                    if (WB16) Cb[(size_t)row * Nout + col] = f2b(v);
                }
            }
        }
    }
}

// ---------------- attention logits from bf16 xh ----------------
__global__ __launch_bounds__(256) void proj_al_kernel(const unsigned short* __restrict__ xhb,
                                                      const float* __restrict__ a_src,
                                                      const float* __restrict__ a_dst,
                                                      float* __restrict__ al_s,
                                                      float* __restrict__ al_d) {
    int n = blockIdx.x * 4 + (threadIdx.x >> 6);
    if (n >= NN) return;
    int lane = threadIdx.x & 63;
    ushort4 v4 = ((const ushort4*)(xhb + (size_t)n * HID))[lane];
    int base = lane * 4;
    float4 as4 = *(const float4*)&a_src[base];
    float4 ad4 = *(const float4*)&a_dst[base];
    float x0 = b2f(v4.x), x1 = b2f(v4.y), x2 = b2f(v4.z), x3 = b2f(v4.w);
    float ps = x0 * as4.x + x1 * as4.y + x2 * as4.z + x3 * as4.w;
    float pd = x0 * ad4.x + x1 * ad4.y + x2 * ad4.z + x3 * ad4.w;
#pragma unroll
    for (int off = 8; off > 0; off >>= 1) {
        ps += __shfl_down(ps, off, 16);
        pd += __shfl_down(pd, off, 16);
    }
    if ((lane & 15) == 0) {
        int h = lane >> 4;
        al_s[n * 4 + h] = ps;
        al_d[n * 4 + h] = pd;
    }
}

// ---------------- wave-per-node: edge softmax + aggregation + LN + ReLU + residual ----------------
__global__ __launch_bounds__(256) void agg_ln_kernel(const int* __restrict__ rowptr,
                                                     const int* __restrict__ csr,
                                                     const float* __restrict__ al_s,
                                                     const float* __restrict__ al_d,
                                                     const unsigned short* __restrict__ xhb,
                                                     const float* __restrict__ bgat,
                                                     const float* __restrict__ g,
                                                     const float* __restrict__ bb,
                                                     float* __restrict__ h,
                                                     unsigned short* __restrict__ hb) {
    int wv = threadIdx.x >> 6, ln = threadIdx.x & 63;
    int n = blockIdx.x * 4 + wv;
    if (n >= NN) return;
    int start = rowptr[n], end = rowptr[n + 1];
    float4 ad = *(const float4*)&al_d[n * 4];

    float d0 = 0.f, d1 = 0.f, d2 = 0.f, d3 = 0.f;
    for (int i = start + ln; i < end; i += 64) {
        int s = csr[i];
        float4 as = *(const float4*)&al_s[s * 4];
        float e0 = as.x + ad.x; e0 = e0 > 0.f ? e0 : NEG * e0;
        float e1 = as.y + ad.y; e1 = e1 > 0.f ? e1 : NEG * e1;
        float e2 = as.z + ad.z; e2 = e2 > 0.f ? e2 : NEG * e2;
        float e3 = as.w + ad.w; e3 = e3 > 0.f ? e3 : NEG * e3;
        d0 += __expf(e0); d1 += __expf(e1); d2 += __expf(e2); d3 += __expf(e3);
    }
#pragma unroll
    for (int off = 32; off > 0; off >>= 1) {
        d0 += __shfl_xor(d0, off, 64);
        d1 += __shfl_xor(d1, off, 64);
        d2 += __shfl_xor(d2, off, 64);
        d3 += __shfl_xor(d3, off, 64);
    }
    int myh = ln >> 4;
    float invh = 1.f / ((myh == 0) ? d0 : (myh == 1) ? d1 : (myh == 2) ? d2 : d3);
    float adh = (myh == 0) ? ad.x : (myh == 1) ? ad.y : (myh == 2) ? ad.z : ad.w;

    float a0 = 0.f, a1 = 0.f, a2 = 0.f, a3 = 0.f;
#pragma unroll 2
    for (int i = start; i < end; i++) {
        int s = csr[i];
        float e = al_s[s * 4 + myh] + adh;
        e = e > 0.f ? e : NEG * e;
        float w = __expf(e) * invh;
        ushort4 mv = *(const ushort4*)&xhb[(size_t)s * HID + ln * 4];
        a0 = fmaf(w, b2f(mv.x), a0);
        a1 = fmaf(w, b2f(mv.y), a1);
        a2 = fmaf(w, b2f(mv.z), a2);
        a3 = fmaf(w, b2f(mv.w), a3);
    }

    float4 bg = *(const float4*)&bgat[ln * 4];
    float v0 = a0 + bg.x, v1 = a1 + bg.y, v2 = a2 + bg.z, v3 = a3 + bg.w;
    float ps = v0 + v1 + v2 + v3;
    float ps2 = v0 * v0 + v1 * v1 + v2 * v2 + v3 * v3;
#pragma unroll
    for (int off = 32; off > 0; off >>= 1) {
        ps += __shfl_xor(ps, off, 64);
        ps2 += __shfl_xor(ps2, off, 64);
    }
    float mu = ps * (1.f / HID);
    float var = ps2 * (1.f / HID) - mu * mu;
    float rs = rsqrtf(var + LNEPS);
    float4 gg = *(const float4*)&g[ln * 4];
    float4 bbv = *(const float4*)&bb[ln * 4];
    float o0 = fmaxf((v0 - mu) * rs * gg.x + bbv.x, 0.f);
    float o1 = fmaxf((v1 - mu) * rs * gg.y + bbv.y, 0.f);
    float o2 = fmaxf((v2 - mu) * rs * gg.z + bbv.z, 0.f);
    float o3 = fmaxf((v3 - mu) * rs * gg.w + bbv.w, 0.f);
    size_t idx = (size_t)n * HID + ln * 4;
    float4 hv = *(const float4*)&h[idx];
    float4 nh = make_float4(hv.x + o0, hv.y + o1, hv.z + o2, hv.w + o3);
    *(float4*)&h[idx] = nh;
    ushort4 nb = {f2b(nh.x), f2b(nh.y), f2b(nh.z), f2b(nh.w)};
    *(ushort4*)&hb[idx] = nb;
}

// ---------------- final tiny GEMM ----------------
__global__ void cls2_kernel(const float* __restrict__ mid, const float* __restrict__ W,
                            const float* __restrict__ bias, float* __restrict__ out) {
    int idx = blockIdx.x * 256 + threadIdx.x;
    if (idx >= NN * NCLS) return;
    int n = idx / NCLS, c = idx % NCLS;
    const float* row = mid + (size_t)n * (HID / 2);
    float acc = bias[c];
#pragma unroll 8
    for (int k = 0; k < HID / 2; k++) acc += row[k] * W[k * NCLS + c];
    out[idx] = acc;
}

extern "C" void kernel_launch(void* const* d_in, const int* in_sizes, int n_in,
                              void* d_out, int out_size, void* d_ws, size_t ws_size,
                              hipStream_t stream) {
    const float* x    = (const float*)d_in[0];
    const int*   ei   = (const int*)d_in[1];
    const float* W_in = (const float*)d_in[2];
    const float* b_in = (const float*)d_in[3];
    const float* W_gat[2]   = {(const float*)d_in[4],  (const float*)d_in[10]};
    const float* att_src[2] = {(const float*)d_in[5],  (const float*)d_in[11]};
    const float* att_dst[2] = {(const float*)d_in[6],  (const float*)d_in[12]};
    const float* b_gat[2]   = {(const float*)d_in[7],  (const float*)d_in[13]};
    const float* ln_g[2]    = {(const float*)d_in[8],  (const float*)d_in[14]};
    const float* ln_b[2]    = {(const float*)d_in[9],  (const float*)d_in[15]};
    const float* W_c1 = (const float*)d_in[16];
    const float* b_c1 = (const float*)d_in[17];
    const float* W_c2 = (const float*)d_in[18];
    const float* b_c2 = (const float*)d_in[19];

    char* ws = (char*)d_ws;
    size_t off = 0;
    auto alloc = [&](size_t bytes) -> void* {
        void* p = ws + off;
        off += (bytes + 255) & ~(size_t)255;
        return p;
    };
    float*          h   = (float*)alloc((size_t)NN * HID * 4);
    unsigned short* hb  = (unsigned short*)alloc((size_t)NN * HID * 2);
    unsigned short* xhb = (unsigned short*)alloc((size_t)NN * HID * 2);
    float* al_s = (float*)alloc((size_t)NN * HEADS * 4);
    float* al_d = (float*)alloc((size_t)NN * HEADS * 4);
    int* rowptr  = (int*)alloc((size_t)(NN + 1) * 4);
    int* cursor  = (int*)alloc((size_t)NN * 4);
    int* csr     = (int*)alloc((size_t)(EE + NN) * 4);
    int* scanned = (int*)alloc((size_t)NN * 4);
    int* chtot   = (int*)alloc(64 * 4);
    unsigned short* WinF = (unsigned short*)alloc((size_t)HID * INDIM * 2);
    unsigned short* WgF0 = (unsigned short*)alloc((size_t)HID * HID * 2);
    unsigned short* WgF1 = (unsigned short*)alloc((size_t)HID * HID * 2);
    unsigned short* Wc1F = (unsigned short*)alloc((size_t)(HID / 2) * HID * 2);
    unsigned short* WgF[2] = {WgF0, WgF1};
    float* mid = (float*)xhb;

    const int* srcv = ei;
    const int* dstv = ei + EE;

    // weight packs (fp32 [K][N] -> bf16 MFMA B-fragment order)
    pack_w_kernel<<<(INDIM * HID / 8 + 255) / 256, 256, 0, stream>>>(W_in, WinF, INDIM, HID);
    pack_w_kernel<<<(HID * HID / 8 + 255) / 256, 256, 0, stream>>>(W_gat[0], WgF0, HID, HID);
    pack_w_kernel<<<(HID * HID / 8 + 255) / 256, 256, 0, stream>>>(W_gat[1], WgF1, HID, HID);
    pack_w_kernel<<<(HID * (HID / 2) / 8 + 255) / 256, 256, 0, stream>>>(W_c1, Wc1F, HID, HID / 2);

    // CSR build
    int nch = (NN + 1023) / 1024;
    init_cnt_kernel<<<(NN + 255) / 256, 256, 0, stream>>>(cursor);
    count_edges_kernel<<<(EE + 255) / 256, 256, 0, stream>>>(dstv, cursor);
    scan1_kernel<<<nch, 1024, 0, stream>>>(cursor, scanned, chtot, NN);
    scan2_kernel<<<1, 64, 0, stream>>>(chtot, nch);
    scan3_kernel<<<(NN + 255) / 256, 256, 0, stream>>>(scanned, chtot, rowptr, NN);
    copyfill_kernel<<<(NN + 255) / 256, 256, 0, stream>>>(rowptr, cursor, csr);
    scatter_edges_kernel<<<(EE + 255) / 256, 256, 0, stream>>>(srcv, dstv, cursor, csr);

    int MB64 = (NN + 63) / 64;  // 782

    // h = relu(x @ W_in + b_in): fp32 A, KI = 1280/64 = 20
    pgemm_kernel<1, 20, 16, 1, 1, 1><<<MB64, 256, 0, stream>>>(
        x, nullptr, WinF, b_in, h, hb, NN);

    for (int l = 0; l < 2; l++) {
        // xh = h @ W_gat: bf16 A, KI = 256/64 = 4
        pgemm_kernel<0, 4, 16, 0, 0, 1><<<MB64, 256, 0, stream>>>(
            nullptr, hb, WgF[l], nullptr, nullptr, xhb, NN);
        proj_al_kernel<<<(NN + 3) / 4, 256, 0, stream>>>(xhb, att_src[l], att_dst[l], al_s, al_d);
        agg_ln_kernel<<<(NN + 3) / 4, 256, 0, stream>>>(rowptr, csr, al_s, al_d, xhb,
                                                        b_gat[l], ln_g[l], ln_b[l], h, hb);
    }

    // classifier: relu(h @ W_c1 + b_c1), N=128 -> NT=8
    pgemm_kernel<0, 4, 8, 1, 1, 0><<<MB64, 256, 0, stream>>>(
        nullptr, hb, Wc1F, b_c1, mid, nullptr, NN);
    cls2_kernel<<<(NN * NCLS + 255) / 256, 256, 0, stream>>>(mid, W_c2, b_c2, (float*)d_out);
}

// Round 6
// 1010.900 us; speedup vs baseline: 1.1495x; 1.0278x over previous
//
#include <hip/hip_runtime.h>

#define NN 50000
#define EE 1600000
#define INDIM 1280
#define HID 256
#define HEADS 4
#define DHD 64
#define NCLS 6
#define NEG 0.2f
#define LNEPS 1e-5f

typedef __attribute__((ext_vector_type(8))) short short8;
typedef __attribute__((ext_vector_type(4))) float floatx4;

__device__ __forceinline__ unsigned short f2b(float f) {
    unsigned int u = __float_as_uint(f);
    u += 0x7FFF + ((u >> 16) & 1);
    return (unsigned short)(u >> 16);
}
__device__ __forceinline__ float b2f(unsigned short b) {
    return __uint_as_float(((unsigned int)b) << 16);
}

// s_waitcnt lgkmcnt(0), vmcnt/expcnt no-wait
#define WAIT_LGKM0() __builtin_amdgcn_s_waitcnt(0xC07F)

// ---------------- CSR build ----------------
__global__ void init_cnt_kernel(int* __restrict__ cnt) {
    int n = blockIdx.x * 256 + threadIdx.x;
    if (n < NN) cnt[n] = 1;  // self loop
}

__global__ void count_edges_kernel(const int* __restrict__ dst, int* __restrict__ cnt) {
    int e = blockIdx.x * 256 + threadIdx.x;
    if (e < EE) atomicAdd(&cnt[dst[e]], 1);
}

__global__ __launch_bounds__(1024) void scan1_kernel(const int* __restrict__ cnt,
                                                     int* __restrict__ scanned,
                                                     int* __restrict__ chtot, int n) {
    __shared__ int wsum[16];
    int tid = threadIdx.x, lane = tid & 63, wv = tid >> 6;
    int i = blockIdx.x * 1024 + tid;
    int s = (i < n) ? cnt[i] : 0;
#pragma unroll
    for (int off = 1; off < 64; off <<= 1) {
        int t = __shfl_up(s, off, 64);
        if (lane >= off) s += t;
    }
    if (lane == 63) wsum[wv] = s;
    __syncthreads();
    if (tid < 16) {
        int ws = wsum[tid];
#pragma unroll
        for (int off = 1; off < 16; off <<= 1) {
            int t = __shfl_up(ws, off, 16);
            if (tid >= off) ws += t;
        }
        wsum[tid] = ws;
    }
    __syncthreads();
    s += (wv > 0) ? wsum[wv - 1] : 0;
    if (i < n) scanned[i] = s;
    if (tid == 1023) chtot[blockIdx.x] = s;
}

__global__ void scan2_kernel(int* __restrict__ chtot, int nch) {
    int lane = threadIdx.x;
    int v = (lane < nch) ? chtot[lane] : 0;
#pragma unroll
    for (int off = 1; off < 64; off <<= 1) {
        int t = __shfl_up(v, off, 64);
        if (lane >= off) v += t;
    }
    if (lane < nch) chtot[lane] = v;
}

__global__ void scan3_kernel(const int* __restrict__ scanned, const int* __restrict__ chtot,
                             int* __restrict__ rowptr, int n) {
    int i = blockIdx.x * 256 + threadIdx.x;
    if (i == 0) rowptr[0] = 0;
    if (i < n) {
        int ch = i >> 10;
        rowptr[i + 1] = scanned[i] + (ch ? chtot[ch - 1] : 0);
    }
}

__global__ void copyfill_kernel(const int* __restrict__ rowptr, int* __restrict__ cursor,
                                int* __restrict__ csr) {
    int n = blockIdx.x * 256 + threadIdx.x;
    if (n < NN) {
        int p = rowptr[n];
        csr[p] = n;
        cursor[n] = p + 1;
    }
}

__global__ void scatter_edges_kernel(const int* __restrict__ src, const int* __restrict__ dst,
                                     int* __restrict__ cursor, int* __restrict__ csr) {
    int e = blockIdx.x * 256 + threadIdx.x;
    if (e < EE) {
        int d = dst[e];
        int pos = atomicAdd(&cursor[d], 1);
        csr[pos] = src[e];
    }
}

// ---------------- weight pack: W[K][N] fp32 -> MFMA B-fragment order bf16 ----------------
__global__ void pack_w_kernel(const float* __restrict__ W, unsigned short* __restrict__ out,
                              int K, int N) {
    int idx = blockIdx.x * 256 + threadIdx.x;
    int total = (K >> 6) * (N >> 4) * 2 * 64;
    if (idx >= total) return;
    int ln = idx & 63;
    int t = idx >> 6;
    int ks = t & 1; t >>= 1;
    int NT = N >> 4;
    int nt = t % NT, kc = t / NT;
    int n = nt * 16 + (ln & 15);
    int k = kc * 64 + ks * 32 + ((ln >> 4) << 3);
    unsigned short u[8];
#pragma unroll
    for (int j = 0; j < 8; j++) u[j] = f2b(W[(size_t)(k + j) * N + n]);
    *(int4*)&out[(size_t)idx * 8] = *(const int4*)u;
}

// ---------------- pipelined LDS-dbuf MFMA GEMM w/ fused epilogues ----------------
// PROJ (NT=16): also emit al_s/al_d attention logits from fp32 acc.
// CLS  (NT=8):  skip C store entirely; emit 6-class logits = relu(acc+bias) @ W2 + b2.
template <int AF32, int KI, int NT, int ACT, int WF32, int WB16, int PROJ, int CLS>
__global__ __launch_bounds__(256) void pgemm_kernel(const float* __restrict__ Af,
                                                    const unsigned short* __restrict__ Ab,
                                                    const unsigned short* __restrict__ Bf,
                                                    const float* __restrict__ bias,
                                                    float* __restrict__ Cf,
                                                    unsigned short* __restrict__ Cb,
                                                    const float* __restrict__ aps,
                                                    const float* __restrict__ apd,
                                                    float* __restrict__ als,
                                                    float* __restrict__ ald,
                                                    const float* __restrict__ W2,
                                                    const float* __restrict__ b2,
                                                    float* __restrict__ out2,
                                                    int M) {
    constexpr int NW = NT / 4;
    constexpr int K = KI * 64;
    __shared__ __align__(16) unsigned short Als[2][4096];  // 2 x 8KB bf16 64x64 tiles
    int tid = threadIdx.x, wv = tid >> 6, ln = tid & 63;
    int m0 = blockIdx.x * 64;

    int srow[2], scol[2];
#pragma unroll
    for (int i = 0; i < 2; i++) {
        int s = tid + i * 256;
        int r = s >> 3;
        srow[i] = min(m0 + r, M - 1);
        scol[i] = ((s & 7) ^ (r & 7)) * 8;
    }

    floatx4 acc[4][NW] = {};
    short8 breg[2][NW * 2];
    float4 af0[4], af1[4];
    int4 ai0[2], ai1[2];

    auto issueA = [&](int k, float4* af, int4* ai) {
#pragma unroll
        for (int i = 0; i < 2; i++) {
            if (AF32) {
                const float* p = Af + (size_t)srow[i] * K + k * 64 + scol[i];
                af[i * 2] = *(const float4*)p;
                af[i * 2 + 1] = *(const float4*)(p + 4);
            } else {
                ai[i] = *(const int4*)(Ab + (size_t)srow[i] * K + k * 64 + scol[i]);
            }
        }
    };
    auto issueB = [&](int k, short8* b) {
#pragma unroll
        for (int nw = 0; nw < NW; nw++)
#pragma unroll
            for (int ks = 0; ks < 2; ks++)
                b[nw * 2 + ks] = *(const short8*)(
                    Bf + ((((size_t)k * NT + (wv * NW + nw)) * 2 + ks) * 64 + ln) * 8);
    };
    auto writeA = [&](int k, const float4* af, const int4* ai) {
        unsigned short* dst = &Als[k & 1][0];
#pragma unroll
        for (int i = 0; i < 2; i++) {
            int4 v;
            if (AF32) {
                unsigned short u[8] = {f2b(af[2 * i].x), f2b(af[2 * i].y),
                                       f2b(af[2 * i].z), f2b(af[2 * i].w),
                                       f2b(af[2 * i + 1].x), f2b(af[2 * i + 1].y),
                                       f2b(af[2 * i + 1].z), f2b(af[2 * i + 1].w)};
                v = *(const int4*)u;
            } else {
                v = ai[i];
            }
            *(int4*)&dst[(tid + i * 256) * 8] = v;
        }
    };
    auto compute = [&](int k, const short8* b) {
        const unsigned short* src = &Als[k & 1][0];
#pragma unroll
        for (int ks = 0; ks < 2; ks++) {
            short8 a[4];
#pragma unroll
            for (int mt = 0; mt < 4; mt++) {
                int row = mt * 16 + (ln & 15);
                int g = ks * 4 + (ln >> 4);
                int off8 = (row >> 3) * 512 + (row & 7) * 64 + (g ^ (row & 7)) * 8;
                a[mt] = *(const short8*)&src[off8];
            }
#pragma unroll
            for (int nw = 0; nw < NW; nw++)
#pragma unroll
                for (int mt = 0; mt < 4; mt++)
                    acc[mt][nw] = __builtin_amdgcn_mfma_f32_16x16x32_bf16(
                        a[mt], b[nw * 2 + ks], acc[mt][nw], 0, 0, 0);
        }
    };

    issueA(0, af0, ai0);
    issueB(0, breg[0]);
    writeA(0, af0, ai0);
    WAIT_LGKM0();
    __builtin_amdgcn_s_barrier();

#pragma unroll
    for (int kk = 0; kk < KI / 2; kk++) {
        int k = kk * 2;
        issueA(k + 1, af1, ai1);
        issueB(k + 1, breg[1]);
        compute(k, breg[0]);
        writeA(k + 1, af1, ai1);
        WAIT_LGKM0();
        __builtin_amdgcn_s_barrier();
        if (k + 2 < KI) {
            issueA(k + 2, af0, ai0);
            issueB(k + 2, breg[0]);
        }
        compute(k + 1, breg[1]);
        if (k + 2 < KI) {
            writeA(k + 2, af0, ai0);
            WAIT_LGKM0();
            __builtin_amdgcn_s_barrier();
        }
    }

    constexpr int Nout = NT * 16;
    // main C store (C/D layout: col=lane&15, row=(lane>>4)*4+reg)
    if constexpr (WF32 || WB16) {
#pragma unroll
        for (int mt = 0; mt < 4; mt++) {
#pragma unroll
            for (int nw = 0; nw < NW; nw++) {
                int col = (wv * NW + nw) * 16 + (ln & 15);
                int rb = m0 + mt * 16 + (ln >> 4) * 4;
                float bi = bias ? bias[col] : 0.f;
#pragma unroll
                for (int r = 0; r < 4; r++) {
                    int row = rb + r;
                    if (row < M) {
                        float v = acc[mt][nw][r] + bi;
                        if (ACT) v = fmaxf(v, 0.f);
                        if (WF32) Cf[(size_t)row * Nout + col] = v;
                        if (WB16) Cb[(size_t)row * Nout + col] = f2b(v);
                    }
                }
            }
        }
    }

    // fused attention-logit projection: wave wv == head wv (cols wv*64..wv*64+63)
    if constexpr (PROJ) {
        float avs[NW], avd[NW];
#pragma unroll
        for (int nw = 0; nw < NW; nw++) {
            int d = nw * 16 + (ln & 15);
            avs[nw] = aps[wv * DHD + d];
            avd[nw] = apd[wv * DHD + d];
        }
#pragma unroll
        for (int mt = 0; mt < 4; mt++) {
#pragma unroll
            for (int r = 0; r < 4; r++) {
                float ssum = 0.f, dsum = 0.f;
#pragma unroll
                for (int nw = 0; nw < NW; nw++) {
                    float v = acc[mt][nw][r];
                    ssum = fmaf(v, avs[nw], ssum);
                    dsum = fmaf(v, avd[nw], dsum);
                }
#pragma unroll
                for (int m = 8; m > 0; m >>= 1) {
                    ssum += __shfl_xor(ssum, m, 16);
                    dsum += __shfl_xor(dsum, m, 16);
                }
                int row = m0 + mt * 16 + (ln >> 4) * 4 + r;
                if ((ln & 15) == 0 && row < M) {
                    als[row * 4 + wv] = ssum;
                    ald[row * 4 + wv] = dsum;
                }
            }
        }
    }

    // fused tiny classifier: logits = relu(acc+bias) @ W2[Nout][6] + b2
    if constexpr (CLS) {
        __shared__ float cred[64][4][NCLS];
        float w2[NW][NCLS];
#pragma unroll
        for (int nw = 0; nw < NW; nw++) {
            int col = (wv * NW + nw) * 16 + (ln & 15);
#pragma unroll
            for (int c = 0; c < NCLS; c++) w2[nw][c] = W2[col * NCLS + c];
        }
#pragma unroll
        for (int mt = 0; mt < 4; mt++) {
#pragma unroll
            for (int r = 0; r < 4; r++) {
                float p[NCLS] = {};
#pragma unroll
                for (int nw = 0; nw < NW; nw++) {
                    int col = (wv * NW + nw) * 16 + (ln & 15);
                    float v = fmaxf(acc[mt][nw][r] + bias[col], 0.f);
#pragma unroll
                    for (int c = 0; c < NCLS; c++) p[c] = fmaf(v, w2[nw][c], p[c]);
                }
#pragma unroll
                for (int m = 8; m > 0; m >>= 1)
#pragma unroll
                    for (int c = 0; c < NCLS; c++) p[c] += __shfl_xor(p[c], m, 16);
                int rl = mt * 16 + (ln >> 4) * 4 + r;
                if ((ln & 15) == 0)
#pragma unroll
                    for (int c = 0; c < NCLS; c++) cred[rl][wv][c] = p[c];
            }
        }
        __syncthreads();
        for (int t = tid; t < 64 * NCLS; t += 256) {
            int row = t / NCLS, c = t % NCLS;
            if (m0 + row < M) {
                float s = cred[row][0][c] + cred[row][1][c] + cred[row][2][c] +
                          cred[row][3][c] + b2[c];
                out2[(size_t)(m0 + row) * NCLS + c] = s;
            }
        }
    }
}

// ---------------- wave-per-node: edge softmax + aggregation + LN + ReLU + residual ----------------
__global__ __launch_bounds__(256) void agg_ln_kernel(const int* __restrict__ rowptr,
                                                     const int* __restrict__ csr,
                                                     const float* __restrict__ al_s,
                                                     const float* __restrict__ al_d,
                                                     const unsigned short* __restrict__ xhb,
                                                     const float* __restrict__ bgat,
                                                     const float* __restrict__ g,
                                                     const float* __restrict__ bb,
                                                     float* __restrict__ h,
                                                     unsigned short* __restrict__ hb) {
    int wv = threadIdx.x >> 6, ln = threadIdx.x & 63;
    int n = blockIdx.x * 4 + wv;
    if (n >= NN) return;
    int start = rowptr[n], end = rowptr[n + 1];
    float4 ad = *(const float4*)&al_d[n * 4];

    // pass A: denominators (4 heads), edges strided over lanes
    float d0 = 0.f, d1 = 0.f, d2 = 0.f, d3 = 0.f;
    for (int i = start + ln; i < end; i += 64) {
        int s = csr[i];
        float4 as = *(const float4*)&al_s[s * 4];
        float e0 = as.x + ad.x; e0 = e0 > 0.f ? e0 : NEG * e0;
        float e1 = as.y + ad.y; e1 = e1 > 0.f ? e1 : NEG * e1;
        float e2 = as.z + ad.z; e2 = e2 > 0.f ? e2 : NEG * e2;
        float e3 = as.w + ad.w; e3 = e3 > 0.f ? e3 : NEG * e3;
        d0 += __expf(e0); d1 += __expf(e1); d2 += __expf(e2); d3 += __expf(e3);
    }
#pragma unroll
    for (int off = 32; off > 0; off >>= 1) {
        d0 += __shfl_xor(d0, off, 64);
        d1 += __shfl_xor(d1, off, 64);
        d2 += __shfl_xor(d2, off, 64);
        d3 += __shfl_xor(d3, off, 64);
    }
    int myh = ln >> 4;
    float invh = 1.f / ((myh == 0) ? d0 : (myh == 1) ? d1 : (myh == 2) ? d2 : d3);
    float adh = (myh == 0) ? ad.x : (myh == 1) ? ad.y : (myh == 2) ? ad.z : ad.w;

    // pass B: weighted row gather, 2 edges in flight (independent FMA chains)
    float p0 = 0.f, p1 = 0.f, p2 = 0.f, p3 = 0.f;
    float q0 = 0.f, q1 = 0.f, q2 = 0.f, q3 = 0.f;
    int i = start;
    for (; i + 1 < end; i += 2) {
        int s0 = csr[i], s1 = csr[i + 1];
        float e0 = al_s[s0 * 4 + myh] + adh; e0 = e0 > 0.f ? e0 : NEG * e0;
        float e1 = al_s[s1 * 4 + myh] + adh; e1 = e1 > 0.f ? e1 : NEG * e1;
        float w0 = __expf(e0) * invh;
        float w1 = __expf(e1) * invh;
        ushort4 u0 = *(const ushort4*)&xhb[(size_t)s0 * HID + ln * 4];
        ushort4 u1 = *(const ushort4*)&xhb[(size_t)s1 * HID + ln * 4];
        p0 = fmaf(w0, b2f(u0.x), p0); q0 = fmaf(w1, b2f(u1.x), q0);
        p1 = fmaf(w0, b2f(u0.y), p1); q1 = fmaf(w1, b2f(u1.y), q1);
        p2 = fmaf(w0, b2f(u0.z), p2); q2 = fmaf(w1, b2f(u1.z), q2);
        p3 = fmaf(w0, b2f(u0.w), p3); q3 = fmaf(w1, b2f(u1.w), q3);
    }
    if (i < end) {
        int s0 = csr[i];
        float e0 = al_s[s0 * 4 + myh] + adh; e0 = e0 > 0.f ? e0 : NEG * e0;
        float w0 = __expf(e0) * invh;
        ushort4 u0 = *(const ushort4*)&xhb[(size_t)s0 * HID + ln * 4];
        p0 = fmaf(w0, b2f(u0.x), p0);
        p1 = fmaf(w0, b2f(u0.y), p1);
        p2 = fmaf(w0, b2f(u0.z), p2);
        p3 = fmaf(w0, b2f(u0.w), p3);
    }
    float a0 = p0 + q0, a1 = p1 + q1, a2 = p2 + q2, a3 = p3 + q3;

    // fused LayerNorm + ReLU + residual (wave-wide over 256 values)
    float4 bg = *(const float4*)&bgat[ln * 4];
    float v0 = a0 + bg.x, v1 = a1 + bg.y, v2 = a2 + bg.z, v3 = a3 + bg.w;
    float ps = v0 + v1 + v2 + v3;
    float ps2 = v0 * v0 + v1 * v1 + v2 * v2 + v3 * v3;
#pragma unroll
    for (int off = 32; off > 0; off >>= 1) {
        ps += __shfl_xor(ps, off, 64);
        ps2 += __shfl_xor(ps2, off, 64);
    }
    float mu = ps * (1.f / HID);
    float var = ps2 * (1.f / HID) - mu * mu;
    float rs = rsqrtf(var + LNEPS);
    float4 gg = *(const float4*)&g[ln * 4];
    float4 bbv = *(const float4*)&bb[ln * 4];
    float o0 = fmaxf((v0 - mu) * rs * gg.x + bbv.x, 0.f);
    float o1 = fmaxf((v1 - mu) * rs * gg.y + bbv.y, 0.f);
    float o2 = fmaxf((v2 - mu) * rs * gg.z + bbv.z, 0.f);
    float o3 = fmaxf((v3 - mu) * rs * gg.w + bbv.w, 0.f);
    size_t idx = (size_t)n * HID + ln * 4;
    float4 hv = *(const float4*)&h[idx];
    float4 nh = make_float4(hv.x + o0, hv.y + o1, hv.z + o2, hv.w + o3);
    *(float4*)&h[idx] = nh;
    ushort4 nb = {f2b(nh.x), f2b(nh.y), f2b(nh.z), f2b(nh.w)};
    *(ushort4*)&hb[idx] = nb;
}

extern "C" void kernel_launch(void* const* d_in, const int* in_sizes, int n_in,
                              void* d_out, int out_size, void* d_ws, size_t ws_size,
                              hipStream_t stream) {
    const float* x    = (const float*)d_in[0];
    const int*   ei   = (const int*)d_in[1];
    const float* W_in = (const float*)d_in[2];
    const float* b_in = (const float*)d_in[3];
    const float* W_gat[2]   = {(const float*)d_in[4],  (const float*)d_in[10]};
    const float* att_src[2] = {(const float*)d_in[5],  (const float*)d_in[11]};
    const float* att_dst[2] = {(const float*)d_in[6],  (const float*)d_in[12]};
    const float* b_gat[2]   = {(const float*)d_in[7],  (const float*)d_in[13]};
    const float* ln_g[2]    = {(const float*)d_in[8],  (const float*)d_in[14]};
    const float* ln_b[2]    = {(const float*)d_in[9],  (const float*)d_in[15]};
    const float* W_c1 = (const float*)d_in[16];
    const float* b_c1 = (const float*)d_in[17];
    const float* W_c2 = (const float*)d_in[18];
    const float* b_c2 = (const float*)d_in[19];

    char* ws = (char*)d_ws;
    size_t off = 0;
    auto alloc = [&](size_t bytes) -> void* {
        void* p = ws + off;
        off += (bytes + 255) & ~(size_t)255;
        return p;
    };
    float*          h   = (float*)alloc((size_t)NN * HID * 4);
    unsigned short* hb  = (unsigned short*)alloc((size_t)NN * HID * 2);
    unsigned short* xhb = (unsigned short*)alloc((size_t)NN * HID * 2);
    float* al_s = (float*)alloc((size_t)NN * HEADS * 4);
    float* al_d = (float*)alloc((size_t)NN * HEADS * 4);
    int* rowptr  = (int*)alloc((size_t)(NN + 1) * 4);
    int* cursor  = (int*)alloc((size_t)NN * 4);
    int* csr     = (int*)alloc((size_t)(EE + NN) * 4);
    int* scanned = (int*)alloc((size_t)NN * 4);
    int* chtot   = (int*)alloc(64 * 4);
    unsigned short* WinF = (unsigned short*)alloc((size_t)HID * INDIM * 2);
    unsigned short* WgF0 = (unsigned short*)alloc((size_t)HID * HID * 2);
    unsigned short* WgF1 = (unsigned short*)alloc((size_t)HID * HID * 2);
    unsigned short* Wc1F = (unsigned short*)alloc((size_t)(HID / 2) * HID * 2);
    unsigned short* WgF[2] = {WgF0, WgF1};

    const int* srcv = ei;
    const int* dstv = ei + EE;

    // weight packs (fp32 [K][N] -> bf16 MFMA B-fragment order)
    pack_w_kernel<<<(INDIM * HID / 8 + 255) / 256, 256, 0, stream>>>(W_in, WinF, INDIM, HID);
    pack_w_kernel<<<(HID * HID / 8 + 255) / 256, 256, 0, stream>>>(W_gat[0], WgF0, HID, HID);
    pack_w_kernel<<<(HID * HID / 8 + 255) / 256, 256, 0, stream>>>(W_gat[1], WgF1, HID, HID);
    pack_w_kernel<<<(HID * (HID / 2) / 8 + 255) / 256, 256, 0, stream>>>(W_c1, Wc1F, HID, HID / 2);

    // CSR build
    int nch = (NN + 1023) / 1024;
    init_cnt_kernel<<<(NN + 255) / 256, 256, 0, stream>>>(cursor);
    count_edges_kernel<<<(EE + 255) / 256, 256, 0, stream>>>(dstv, cursor);
    scan1_kernel<<<nch, 1024, 0, stream>>>(cursor, scanned, chtot, NN);
    scan2_kernel<<<1, 64, 0, stream>>>(chtot, nch);
    scan3_kernel<<<(NN + 255) / 256, 256, 0, stream>>>(scanned, chtot, rowptr, NN);
    copyfill_kernel<<<(NN + 255) / 256, 256, 0, stream>>>(rowptr, cursor, csr);
    scatter_edges_kernel<<<(EE + 255) / 256, 256, 0, stream>>>(srcv, dstv, cursor, csr);

    int MB64 = (NN + 63) / 64;  // 782

    // h = relu(x @ W_in + b_in): fp32 A, KI=20
    pgemm_kernel<1, 20, 16, 1, 1, 1, 0, 0><<<MB64, 256, 0, stream>>>(
        x, nullptr, WinF, b_in, h, hb,
        nullptr, nullptr, nullptr, nullptr, nullptr, nullptr, nullptr, NN);

    for (int l = 0; l < 2; l++) {
        // xh = h @ W_gat (bf16 out) + fused al_src/al_dst projection
        pgemm_kernel<0, 4, 16, 0, 0, 1, 1, 0><<<MB64, 256, 0, stream>>>(
            nullptr, hb, WgF[l], nullptr, nullptr, xhb,
            att_src[l], att_dst[l], al_s, al_d, nullptr, nullptr, nullptr, NN);
        agg_ln_kernel<<<(NN + 3) / 4, 256, 0, stream>>>(rowptr, csr, al_s, al_d, xhb,
                                                        b_gat[l], ln_g[l], ln_b[l], h, hb);
    }

    // classifier: logits = relu(h @ W_c1 + b_c1) @ W_c2 + b_c2, fully fused
    pgemm_kernel<0, 4, 8, 1, 0, 0, 0, 1><<<MB64, 256, 0, stream>>>(
        nullptr, hb, Wc1F, b_c1, nullptr, nullptr,
        nullptr, nullptr, nullptr, nullptr, W_c2, b_c2, (float*)d_out, NN);
}